// Round 12
// baseline (2805.585 us; speedup 1.0000x reference)
//
#include <hip/hip_runtime.h>

typedef unsigned short u16;
typedef unsigned int u32;
typedef _Float16 f16;
typedef __attribute__((ext_vector_type(8))) _Float16 f16x8;
typedef __attribute__((ext_vector_type(4))) float f32x4;

#define NN 40000
#define EE 100000
#define DD 64
#define BB 256
#define XTS 68   // s_xT stride (f32): 272B = 16B-aligned rows, bank-spread
#define EPB 64   // edges per block; 4 waves = 4 ft-groups (16 cols each)

__device__ inline float sigmoidf_(float x){
    return 1.f / (1.f + __expf(-x));
}
__device__ inline float tanhf_(float x){
    x = fmaxf(fminf(x, 15.f), -15.f);
    float e = __expf(2.f * x);
    return (e - 1.f) / (e + 1.f);
}

// ---------------- prep: transposes, f16 convert, eff bias, offsets -----------
__global__ __launch_bounds__(256) void prep_kernel(
    const float* __restrict__ en_w2, f16* __restrict__ w2h,
    const float* __restrict__ gru_wih, const float* __restrict__ gru_whh,
    float* __restrict__ wTs,
    const float* __restrict__ ls_wih0, const float* __restrict__ ls_wih12,
    const float* __restrict__ ls_whh, float* __restrict__ lsT,
    const float* __restrict__ lin3_w, float* __restrict__ lin3T,
    const float* __restrict__ gru_bih, const float* __restrict__ conv_b,
    float* __restrict__ effb,
    const int* __restrict__ node_graph, int* __restrict__ offs)
{
    int i = blockIdx.x * 256 + threadIdx.x;
    if (i < 524288){
        w2h[i] = (f16)en_w2[i];
        return;
    }
    i -= 524288;
    if (i < 24576){
        int which = i / 12288, r = i % 12288;
        int d = r / 192, g = r % 192;
        const float* W = which ? gru_whh : gru_wih;
        wTs[which * 12288 + d * 192 + g] = W[g * 64 + d];
        return;
    }
    i -= 24576;
    if (i < 114688){
        float v;
        if (i < 32768){
            int d = i >> 8, g = i & 255;
            v = ls_wih0[g * 128 + d];
        } else if (i < 65536){
            int j = i - 32768;
            int l = j >> 14, r = j & 16383;
            int d = r >> 8, g = r & 255;
            v = ls_wih12[l * 16384 + g * 64 + d];
        } else {
            int j = i - 65536;
            int l = j >> 14, r = j & 16383;
            int d = r >> 8, g = r & 255;
            v = ls_whh[l * 16384 + g * 64 + d];
        }
        lsT[i] = v;
        return;
    }
    i -= 114688;
    if (i < 16384){
        int ii = i >> 7, jj = i & 127;
        lin3T[i] = lin3_w[jj * 128 + ii];
        return;
    }
    i -= 16384;
    if (i < 192){
        float b = gru_bih[i];
        #pragma unroll
        for (int d = 0; d < 64; d++) b += gru_wih[i * 64 + d] * conv_b[d];
        effb[i] = b;
        return;
    }
    i -= 192;
    if (i <= 256){
        int lo = 0, hi = NN;
        while (lo < hi){
            int mid = (lo + hi) >> 1;
            if (node_graph[mid] < i) lo = mid + 1; else hi = mid;
        }
        offs[i] = lo;
        return;
    }
}

// ---------------- lin0: out = n_feat @ lin0_w^T + b  (writes h in d_out) -----
__global__ __launch_bounds__(256) void lin0_kernel(
    const float* __restrict__ nf, const float* __restrict__ w,
    const float* __restrict__ b, float* __restrict__ out)
{
    int tid = blockIdx.x * 256 + threadIdx.x;
    int n = tid >> 6, d = tid & 63;
    if (n >= NN) return;
    float acc = b[d];
    const float* nr = nf + (size_t)n * 23;
    const float* wr = w + d * 23;
    #pragma unroll
    for (int j = 0; j < 23; j++) acc = fmaf(nr[j], wr[j], acc);
    out[(size_t)n * 64 + d] = acc;
}

// ---------------- edge hidden: relu(e_feat @ w1^T + b1) -> f16 hi/lo ---------
__global__ __launch_bounds__(256) void edge_hidden_kernel(
    const float* __restrict__ ef, const float* __restrict__ w1,
    const float* __restrict__ b1, f16* __restrict__ hidh, f16* __restrict__ hidl)
{
    int tid = blockIdx.x * 256 + threadIdx.x;
    int e = tid >> 7, k = tid & 127;
    if (e >= EE) return;
    float acc = b1[k];
    const float* er = ef + (size_t)e * 19;
    const float* wr = w1 + k * 19;
    #pragma unroll
    for (int j = 0; j < 19; j++) acc = fmaf(er[j], wr[j], acc);
    acc = fmaxf(acc, 0.f);
    f16 hi = (f16)acc;
    f16 lo = (f16)(acc - (float)hi);
    hidh[(size_t)e * 128 + k] = hi;
    hidl[(size_t)e * 128 + k] = lo;
}

// ---------------- fused msg: ft-split waves, B slice per wave ---------------
// msg[e,f] = sum_d x[e,d] * ( sum_k u[e,k]*W2[d*64+f,k] + b2[d*64+f] )
// block = 64 edges; wave wid owns cols [wid*16, wid*16+16) for ALL 64 edges
// (mt=4). K=128 time-split over 2 passes (hi+lo half-K A = 64 VGPR). Each
// wave reads only ITS 2KB B-slice per d (no cross-wave duplication -> LDS
// traffic 8x lower than R10/R11). B slots: col*8 + (j ^ (col&7)) -> fixed-j
// reads are 2-way (free); linear writes 2-way. s_xT transposed (stride 68)
// -> xv = 4 broadcast b128 reads per d. LDS 33.9KB -> 4 blocks/CU.
__global__ __launch_bounds__(256) void msg_fused_kernel(
    const float* __restrict__ h, const f16* __restrict__ hidh,
    const f16* __restrict__ hidl, const f16* __restrict__ w2h,
    const float* __restrict__ b2, const int* __restrict__ src,
    const int* __restrict__ dst, float* __restrict__ m)
{
    __shared__ float s_xT[64 * XTS];         // [d][el] transposed x
    __shared__ int s_dst[EPB];
    __shared__ f16x8 s_b[2][512];            // 2 x 8KB half-K B tiles

    const int t = threadIdx.x;
    const int base = blockIdx.x * EPB;
    for (int i = t; i < EPB * 64; i += 256){
        int el = i >> 6, f = i & 63;
        int e = base + el;
        float v = 0.f;
        if (e < EE) v = h[(size_t)src[e] * 64 + f];
        s_xT[f * XTS + el] = v;
    }
    if (t < EPB){
        int e = base + t;
        s_dst[t] = (e < EE) ? dst[e] : -1;
    }

    const int lane = t & 63;
    const int wid = t >> 6;                  // ft group: cols wid*16..wid*16+15
    const int r16 = lane & 15;
    const int kg = lane >> 4;

    f32x4 msg[4];                            // [mt]: 16 VGPR, lives both passes
    #pragma unroll
    for (int a = 0; a < 4; a++){
        f32x4 z = {0.f, 0.f, 0.f, 0.f};
        msg[a] = z;
    }

    const float* __restrict__ b2w = b2 + wid * 16 + r16;
    const int slotb = (wid * 16 + r16) * 8;
    const int sw = r16 & 7;
    f16x8 stg[2];

    // stage tile (DN, kh): 512 slots of 16B; slot c holds element
    // (col=c>>3, jj=(c&7)^(col&7)) of W2[d*64+col][kh*64 + jj*8 ..]
#define STGLD(DN)                                                            \
    {                                                                        \
        const f16* gsrc = w2h + (size_t)(DN) * 8192 + kh * 64;               \
        _Pragma("unroll")                                                    \
        for (int cc = 0; cc < 2; cc++){                                      \
            int c = t + cc * 256;                                            \
            int col = c >> 3;                                                \
            int jj = (c & 7) ^ (col & 7);                                    \
            stg[cc] = *(const f16x8*)(gsrc + col * 128 + jj * 8);            \
        }                                                                    \
    }
#define STGWR(BUF)                                                           \
    {                                                                        \
        s_b[BUF][t] = stg[0];                                                \
        s_b[BUF][t + 256] = stg[1];                                          \
    }

    for (int kh = 0; kh < 2; kh++){
        // A fragments (hi and lo) for this k-half: 16 frags = 64 VGPR
        f16x8 ah[4][2], al[4][2];
        #pragma unroll
        for (int mt = 0; mt < 4; mt++){
            int e = base + mt * 16 + r16;
            #pragma unroll
            for (int ks = 0; ks < 2; ks++){
                int koff = kh * 64 + ks * 32 + kg * 8;
                if (e < EE){
                    ah[mt][ks] = *(const f16x8*)(hidh + (size_t)e * 128 + koff);
                    al[mt][ks] = *(const f16x8*)(hidl + (size_t)e * 128 + koff);
                } else {
                    f16x8 z = {0,0,0,0,0,0,0,0};
                    ah[mt][ks] = z; al[mt][ks] = z;
                }
            }
        }

        STGLD(0); STGWR(0);
        __syncthreads();                     // also covers s_xT/s_dst on kh=0

        for (int d = 0; d < 64; d++){
            int cur = d & 1;
            if (d < 63) STGLD(d + 1);        // issue global loads early (T14)
            f32x4 xv[4];
            #pragma unroll
            for (int mt = 0; mt < 4; mt++)
                xv[mt] = *(const f32x4*)&s_xT[d * XTS + mt * 16 + kg * 4];
            f16x8 bf0 = s_b[cur][slotb + (kg ^ sw)];
            f16x8 bf1 = s_b[cur][slotb + ((4 | kg) ^ sw)];
            float b2v = (kh == 0) ? b2w[d * 64] : 0.f;
            #pragma unroll
            for (int mt = 0; mt < 4; mt++){
                f32x4 acc = {b2v, b2v, b2v, b2v};
                acc = __builtin_amdgcn_mfma_f32_16x16x32_f16(ah[mt][0], bf0, acc, 0, 0, 0);
                acc = __builtin_amdgcn_mfma_f32_16x16x32_f16(al[mt][0], bf0, acc, 0, 0, 0);
                acc = __builtin_amdgcn_mfma_f32_16x16x32_f16(ah[mt][1], bf1, acc, 0, 0, 0);
                acc = __builtin_amdgcn_mfma_f32_16x16x32_f16(al[mt][1], bf1, acc, 0, 0, 0);
                msg[mt] = xv[mt] * acc + msg[mt];
            }
            if (d < 63) STGWR(cur ^ 1);      // write late, after MFMAs
            __syncthreads();
        }
    }
#undef STGLD
#undef STGWR

    // scatter-add: each wave owns its 16-col slice of all 64 edges
    #pragma unroll
    for (int mt = 0; mt < 4; mt++){
        #pragma unroll
        for (int r = 0; r < 4; r++){
            int el = mt * 16 + kg * 4 + r;
            int dt = s_dst[el];
            if (dt >= 0)
                atomicAdd(&m[(size_t)dt * 64 + wid * 16 + r16], msg[mt][r]);
        }
    }
}

// ---------------- GRU GEMM: G[n,g] = bias[g] + sum_d X[n,d]*wT[d,g], g<192 ---
__global__ __launch_bounds__(128) void gru_gemm_kernel(
    const float* __restrict__ m, const float* __restrict__ h,
    const float* __restrict__ wTs, const float* __restrict__ effb,
    const float* __restrict__ bhh,
    float* __restrict__ gi, float* __restrict__ gh)
{
    const int which = blockIdx.y;
    const float* __restrict__ X = which ? h : m;
    const float* __restrict__ wT = wTs + which * (64 * 192);
    const float* __restrict__ bias = which ? bhh : effb;
    float* __restrict__ G = which ? gh : gi;
    const int n0 = blockIdx.x * 128;
    const int t = threadIdx.x;
    __shared__ float s_x[128][65];
    __shared__ float s_b[128][17];
    for (int i = t; i < 128 * 64; i += 128){
        int nn = i >> 6, d = i & 63;
        int n = n0 + nn;
        s_x[nn][d] = (n < NN) ? X[(size_t)n * 64 + d] : 0.f;
    }
    __syncthreads();
    for (int gc = 0; gc < 12; gc++){
        float acc[16];
        #pragma unroll
        for (int j = 0; j < 16; j++) acc[j] = bias[gc * 16 + j];
        #pragma unroll 4
        for (int d = 0; d < 64; d++){
            float xv = s_x[t][d];
            const float* wr = wT + d * 192 + gc * 16;
            #pragma unroll
            for (int j = 0; j < 16; j++) acc[j] = fmaf(xv, wr[j], acc[j]);
        }
        #pragma unroll
        for (int j = 0; j < 16; j++) s_b[t][j] = acc[j];
        __syncthreads();
        for (int i = t; i < 128 * 16; i += 128){
            int nn = i >> 4, j = i & 15;
            int n = n0 + nn;
            if (n < NN) G[(size_t)n * 192 + gc * 16 + j] = s_b[nn][j];
        }
        __syncthreads();
    }
}

// ---------------- GRU gates: h' = (1-z)*n + z*h --------------------------
__global__ __launch_bounds__(256) void gru_gate_kernel(
    const float* __restrict__ gi, const float* __restrict__ gh,
    float* __restrict__ h)
{
    int tid = blockIdx.x * 256 + threadIdx.x;
    int n = tid >> 6, f = tid & 63;
    if (n >= NN) return;
    size_t b = (size_t)n * 192;
    float ir = gi[b + f], iz = gi[b + 64 + f], inn = gi[b + 128 + f];
    float hr = gh[b + f], hz = gh[b + 64 + f], hn = gh[b + 128 + f];
    float r = sigmoidf_(ir + hr);
    float z = sigmoidf_(iz + hz);
    float nv = tanhf_(inn + r * hn);
    size_t hb = (size_t)n * 64 + f;
    float hv = h[hb];
    h[hb] = (1.f - z) * nv + z * hv;
}

// ---------------- Set2Set + final projection: one block per graph ------------
__global__ __launch_bounds__(256) void set2set_kernel(
    const float* __restrict__ out, const int* __restrict__ offs,
    const float* __restrict__ lsT, const float* __restrict__ ls_bih,
    const float* __restrict__ ls_bhh, const float* __restrict__ lin3T,
    const float* __restrict__ lin3_b, const float* __restrict__ pred_w,
    const float* __restrict__ pred_b, float* __restrict__ e_ws,
    float* __restrict__ pred_out)
{
    int g = blockIdx.x;
    int t = threadIdx.x;
    int ln = t >> 6, d = t & 63;
    __shared__ float s_qstar[128], s_h[3][64], s_c[3][64], s_g[256];
    __shared__ float s_r[4][64], s_red[4], s_wsum[4], s_y[128];
    if (t < 128) s_qstar[t] = 0.f;
    if (t < 192){ s_h[t / 64][t % 64] = 0.f; s_c[t / 64][t % 64] = 0.f; }
    int ns = offs[g], ne = offs[g + 1];
    __syncthreads();

    for (int it = 0; it < 6; it++){
        for (int l = 0; l < 3; l++){
            const float* xv = (l == 0) ? s_qstar : s_h[l - 1];
            int xdim = (l == 0) ? 128 : 64;
            const float* wxT = lsT + ((l == 0) ? 0 : (32768 + (l - 1) * 16384));
            const float* whT = lsT + 65536 + l * 16384;
            float acc = ls_bih[l * 256 + t] + ls_bhh[l * 256 + t];
            for (int j = 0; j < xdim; j++) acc = fmaf(xv[j], wxT[j * 256 + t], acc);
            #pragma unroll 4
            for (int j = 0; j < 64; j++) acc = fmaf(s_h[l][j], whT[j * 256 + t], acc);
            __syncthreads();
            s_g[t] = acc;
            __syncthreads();
            if (t < 64){
                float iv = s_g[t], fv = s_g[64 + t], gv = s_g[128 + t], ov = s_g[192 + t];
                float c2 = sigmoidf_(fv) * s_c[l][t] + sigmoidf_(iv) * tanhf_(gv);
                float h2 = sigmoidf_(ov) * tanhf_(c2);
                s_c[l][t] = c2; s_h[l][t] = h2;
            }
            __syncthreads();
        }
        float wmax = -3.4e38f;
        for (int n = ns + ln; n < ne; n += 4){
            float p = out[(size_t)n * 64 + d] * s_h[2][d];
            #pragma unroll
            for (int o = 1; o < 64; o <<= 1) p += __shfl_xor(p, o);
            if (d == 0) e_ws[n] = p;
            wmax = fmaxf(wmax, p);
        }
        if (d == 0) s_red[ln] = wmax;
        __syncthreads();
        float gmax = fmaxf(fmaxf(s_red[0], s_red[1]), fmaxf(s_red[2], s_red[3]));
        float wsum = 0.f, racc = 0.f;
        for (int n = ns + ln; n < ne; n += 4){
            float w = __expf(e_ws[n] - gmax);
            wsum += w;
            racc = fmaf(w, out[(size_t)n * 64 + d], racc);
        }
        s_r[ln][d] = racc;
        if (d == 0) s_wsum[ln] = wsum;
        __syncthreads();
        if (t < 64){
            float gsum = s_wsum[0] + s_wsum[1] + s_wsum[2] + s_wsum[3];
            float ro = s_r[0][t] + s_r[1][t] + s_r[2][t] + s_r[3][t];
            ro = (gsum > 0.f) ? ro / gsum : 0.f;
            s_qstar[t] = s_h[2][t];
            s_qstar[64 + t] = ro;
        }
        __syncthreads();
    }
    if (t < 128){
        float acc = lin3_b[t];
        #pragma unroll 4
        for (int i = 0; i < 128; i++) acc = fmaf(s_qstar[i], lin3T[i * 128 + t], acc);
        s_y[t] = fmaxf(acc, 0.f);
    }
    __syncthreads();
    if (t < 64){
        float p = s_y[t] * pred_w[t] + s_y[64 + t] * pred_w[64 + t];
        #pragma unroll
        for (int o = 1; o < 64; o <<= 1) p += __shfl_xor(p, o);
        if (t == 0) pred_out[g] = p + pred_b[0];
    }
}

extern "C" void kernel_launch(void* const* d_in, const int* in_sizes, int n_in,
                              void* d_out, int out_size, void* d_ws, size_t ws_size,
                              hipStream_t stream)
{
    (void)in_sizes; (void)n_in; (void)out_size; (void)ws_size;
    const float* n_feat  = (const float*)d_in[0];
    const float* e_feat  = (const float*)d_in[1];
    const int*   src     = (const int*)d_in[2];
    const int*   dst     = (const int*)d_in[3];
    const int*   node_graph = (const int*)d_in[4];
    const float* lin0_w  = (const float*)d_in[6];
    const float* lin0_b  = (const float*)d_in[7];
    const float* en_w1   = (const float*)d_in[8];
    const float* en_b1   = (const float*)d_in[9];
    const float* en_w2   = (const float*)d_in[10];
    const float* en_b2   = (const float*)d_in[11];
    const float* conv_b  = (const float*)d_in[12];
    const float* gru_wih = (const float*)d_in[13];
    const float* gru_whh = (const float*)d_in[14];
    const float* gru_bih = (const float*)d_in[15];
    const float* gru_bhh = (const float*)d_in[16];
    const float* ls_wih0 = (const float*)d_in[17];
    const float* ls_wih12= (const float*)d_in[18];
    const float* ls_whh  = (const float*)d_in[19];
    const float* ls_bih  = (const float*)d_in[20];
    const float* ls_bhh  = (const float*)d_in[21];
    const float* lin3_w  = (const float*)d_in[22];
    const float* lin3_b  = (const float*)d_in[23];
    const float* pred_w  = (const float*)d_in[24];
    const float* pred_b  = (const float*)d_in[25];

    float* h = (float*)d_out;                       // N x 64 (also "out")
    float* pred_out = (float*)d_out + (size_t)NN * 64;

    char* ws = (char*)d_ws;
    f16*   hidh  = (f16*)(ws + 0);                  // 25,600,000
    f16*   hidl  = (f16*)(ws + 25600000);           // 25,600,000
    float* m     = (float*)(ws + 51200000);         // 10,240,000
    float* gi    = (float*)(ws + 61440000);         // 30,720,000
    float* gh    = (float*)(ws + 92160000);         // 30,720,000
    f16*   w2h   = (f16*)(ws + 122880000);          //  1,048,576
    float* wTs   = (float*)(ws + 123928576);        //     98,304
    float* lsT   = (float*)(ws + 124026880);        //    458,752
    float* lin3T = (float*)(ws + 124485632);        //     65,536
    float* effb  = (float*)(ws + 124551168);        //        768
    float* e_ws  = (float*)(ws + 124551936);        //    160,000
    int*   offs  = (int*)(ws + 124711936);          //      1,028

    prep_kernel<<<2658, 256, 0, stream>>>(en_w2, w2h, gru_wih, gru_whh, wTs,
                                          ls_wih0, ls_wih12, ls_whh, lsT,
                                          lin3_w, lin3T, gru_bih, conv_b, effb,
                                          node_graph, offs);
    lin0_kernel<<<(NN * 64) / 256, 256, 0, stream>>>(n_feat, lin0_w, lin0_b, h);
    edge_hidden_kernel<<<(EE * 128) / 256, 256, 0, stream>>>(e_feat, en_w1, en_b1, hidh, hidl);

    for (int step = 0; step < 6; step++){
        hipMemsetAsync(m, 0, (size_t)NN * 64 * sizeof(float), stream);
        msg_fused_kernel<<<(EE + EPB - 1) / EPB, 256, 0, stream>>>(h, hidh, hidl, w2h,
                                                                   en_b2, src, dst, m);
        dim3 gg((NN + 127) / 128, 2);
        gru_gemm_kernel<<<gg, 128, 0, stream>>>(m, h, wTs, effb, gru_bhh, gi, gh);
        gru_gate_kernel<<<(NN * 64) / 256, 256, 0, stream>>>(gi, gh, h);
    }

    set2set_kernel<<<BB, 256, 0, stream>>>(h, offs, lsT, ls_bih, ls_bhh,
                                           lin3T, lin3_b, pred_w, pred_b,
                                           e_ws, pred_out);
}

// Round 13
// 1802.688 us; speedup vs baseline: 1.5563x; 1.5563x over previous
//
#include <hip/hip_runtime.h>

typedef unsigned short u16;
typedef unsigned int u32;
typedef _Float16 f16;
typedef __attribute__((ext_vector_type(8))) _Float16 f16x8;
typedef __attribute__((ext_vector_type(4))) float f32x4;

#define NN 40000
#define EE 100000
#define DD 64
#define BB 256
#define XTS 68   // s_xT stride (f32): 16B-aligned rows
#define EPB 64   // edges per block; 4 waves = 2 edge-groups x 2 col-pairs

__device__ inline float sigmoidf_(float x){
    return 1.f / (1.f + __expf(-x));
}
__device__ inline float tanhf_(float x){
    x = fmaxf(fminf(x, 15.f), -15.f);
    float e = __expf(2.f * x);
    return (e - 1.f) / (e + 1.f);
}

// ---------------- prep: converts, transposes, eff bias, offsets --------------
__global__ __launch_bounds__(256) void prep_kernel(
    const float* __restrict__ en_w2, f16* __restrict__ w2h,
    const float* __restrict__ gru_wih, const float* __restrict__ gru_whh,
    f16* __restrict__ wf16h, f16* __restrict__ wf16l,
    const float* __restrict__ ls_wih0, const float* __restrict__ ls_wih12,
    const float* __restrict__ ls_whh, float* __restrict__ lsT,
    const float* __restrict__ lin3_w, float* __restrict__ lin3T,
    const float* __restrict__ gru_bih, const float* __restrict__ conv_b,
    float* __restrict__ effb,
    const int* __restrict__ node_graph, int* __restrict__ offs)
{
    int i = blockIdx.x * 256 + threadIdx.x;
    if (i < 524288){
        w2h[i] = (f16)en_w2[i];
        return;
    }
    i -= 524288;
    if (i < 49152){                       // GRU weights -> f16 hi/lo, [gg][g][d]
        int sel = i / 12288;              // 0:ih-hi 1:ih-lo 2:hh-hi 3:hh-lo
        int r = i % 12288;
        int gg = sel >> 1, islo = sel & 1;
        float v = (gg ? gru_whh : gru_wih)[r];
        f16 hi = (f16)v;
        if (islo) wf16l[gg * 12288 + r] = (f16)(v - (float)hi);
        else      wf16h[gg * 12288 + r] = hi;
        return;
    }
    i -= 49152;
    if (i < 114688){
        float v;
        if (i < 32768){
            int d = i >> 8, g = i & 255;
            v = ls_wih0[g * 128 + d];
        } else if (i < 65536){
            int j = i - 32768;
            int l = j >> 14, r = j & 16383;
            int d = r >> 8, g = r & 255;
            v = ls_wih12[l * 16384 + g * 64 + d];
        } else {
            int j = i - 65536;
            int l = j >> 14, r = j & 16383;
            int d = r >> 8, g = r & 255;
            v = ls_whh[l * 16384 + g * 64 + d];
        }
        lsT[i] = v;
        return;
    }
    i -= 114688;
    if (i < 16384){
        int ii = i >> 7, jj = i & 127;
        lin3T[i] = lin3_w[jj * 128 + ii];
        return;
    }
    i -= 16384;
    if (i < 192){
        float b = gru_bih[i];
        #pragma unroll
        for (int d = 0; d < 64; d++) b += gru_wih[i * 64 + d] * conv_b[d];
        effb[i] = b;
        return;
    }
    i -= 192;
    if (i <= 256){
        int lo = 0, hi = NN;
        while (lo < hi){
            int mid = (lo + hi) >> 1;
            if (node_graph[mid] < i) lo = mid + 1; else hi = mid;
        }
        offs[i] = lo;
        return;
    }
}

// ---------------- lin0: out = n_feat @ lin0_w^T + b  (writes h in d_out) -----
__global__ __launch_bounds__(256) void lin0_kernel(
    const float* __restrict__ nf, const float* __restrict__ w,
    const float* __restrict__ b, float* __restrict__ out)
{
    int tid = blockIdx.x * 256 + threadIdx.x;
    int n = tid >> 6, d = tid & 63;
    if (n >= NN) return;
    float acc = b[d];
    const float* nr = nf + (size_t)n * 23;
    const float* wr = w + d * 23;
    #pragma unroll
    for (int j = 0; j < 23; j++) acc = fmaf(nr[j], wr[j], acc);
    out[(size_t)n * 64 + d] = acc;
}

// ---------------- edge hidden: relu(e_feat @ w1^T + b1) -> f16 hi/lo ---------
__global__ __launch_bounds__(256) void edge_hidden_kernel(
    const float* __restrict__ ef, const float* __restrict__ w1,
    const float* __restrict__ b1, f16* __restrict__ hidh, f16* __restrict__ hidl)
{
    int tid = blockIdx.x * 256 + threadIdx.x;
    int e = tid >> 7, k = tid & 127;
    if (e >= EE) return;
    float acc = b1[k];
    const float* er = ef + (size_t)e * 19;
    const float* wr = w1 + k * 19;
    #pragma unroll
    for (int j = 0; j < 19; j++) acc = fmaf(er[j], wr[j], acc);
    acc = fmaxf(acc, 0.f);
    f16 hi = (f16)acc;
    f16 lo = (f16)(acc - (float)hi);
    hidh[(size_t)e * 128 + k] = hi;
    hidl[(size_t)e * 128 + k] = lo;
}

// ---------------- fused msg: single-pass full-K, 2eg x 2colpair waves -------
// msg[e,f] = sum_d x[e,d] * ( sum_k u[e,k]*W2[d*64+f,k] + b2[d*64+f] )
// block = 64 edges; wave (eg, fp) owns edges [eg*32,+32) x cols [fp*32,+32).
// Full K resident (A hi/lo = 64 VGPR), acc only 16, one barrier per d,
// A loaded once (fixes R12's 2-pass). B LDS reads: 8KB/wave/d (2x dup vs
// R10's 4x). Staging = R12's proven conflict-free pre-swizzled-source
// scheme (600K conflicts): slot c holds piece j=(c&8)|((c&7)^(col&7)).
__global__ __launch_bounds__(256) void msg_fused_kernel(
    const float* __restrict__ h, const f16* __restrict__ hidh,
    const f16* __restrict__ hidl, const f16* __restrict__ w2h,
    const float* __restrict__ b2, const int* __restrict__ src,
    const int* __restrict__ dst, float* __restrict__ m)
{
    __shared__ float s_xT[64 * XTS];         // [d][el] transposed x
    __shared__ int s_dst[EPB];
    __shared__ f16x8 s_b[2][1024];           // 2 x 16 KB full-K B tiles

    const int t = threadIdx.x;
    const int base = blockIdx.x * EPB;
    for (int i = t; i < EPB * 64; i += 256){
        int el = i >> 6, f = i & 63;
        int e = base + el;
        float v = 0.f;
        if (e < EE) v = h[(size_t)src[e] * 64 + f];
        s_xT[f * XTS + el] = v;
    }
    if (t < EPB){
        int e = base + t;
        s_dst[t] = (e < EE) ? dst[e] : -1;
    }

    const int lane = t & 63;
    const int wid = t >> 6;
    const int eg = wid >> 1;                 // edge group: 32 edges
    const int fp = wid & 1;                  // col pair: cols fp*32..fp*32+31
    const int r16 = lane & 15;
    const int kg = lane >> 4;
    const int we = eg * 32;

    // A fragments (hi and lo), full K: 16 frags = 64 VGPR
    f16x8 ah[2][4], al[2][4];
    #pragma unroll
    for (int mt = 0; mt < 2; mt++){
        int e = base + we + mt * 16 + r16;
        #pragma unroll
        for (int ks = 0; ks < 4; ks++){
            if (e < EE){
                ah[mt][ks] = *(const f16x8*)(hidh + (size_t)e * 128 + ks * 32 + kg * 8);
                al[mt][ks] = *(const f16x8*)(hidl + (size_t)e * 128 + ks * 32 + kg * 8);
            } else {
                f16x8 z = {0,0,0,0,0,0,0,0};
                ah[mt][ks] = z; al[mt][ks] = z;
            }
        }
    }

    f32x4 msg[2][2];                         // [mt][ftl]: 16 VGPR
    #pragma unroll
    for (int a = 0; a < 2; a++)
        #pragma unroll
        for (int b = 0; b < 2; b++){
            f32x4 z = {0.f, 0.f, 0.f, 0.f};
            msg[a][b] = z;
        }

    f16x8 stg[4];
#define STGLD(DN)                                                            \
    {                                                                        \
        const f16* gsrc = w2h + (size_t)(DN) * 8192;                         \
        _Pragma("unroll")                                                    \
        for (int cc = 0; cc < 4; cc++){                                      \
            int c = t + cc * 256;                                            \
            int col = c >> 4;                                                \
            int j = (c & 8) | ((c & 7) ^ (col & 7));                         \
            stg[cc] = *(const f16x8*)(gsrc + col * 128 + j * 8);             \
        }                                                                    \
    }
#define STGWR(BUF)                                                           \
    {                                                                        \
        _Pragma("unroll")                                                    \
        for (int cc = 0; cc < 4; cc++)                                       \
            s_b[BUF][t + cc * 256] = stg[cc];                                \
    }

    STGLD(0); STGWR(0);
    __syncthreads();

    for (int d = 0; d < 64; d++){
        int cur = d & 1;
        if (d < 63) STGLD(d + 1);            // issue global loads early
        f32x4 xv[2];
        #pragma unroll
        for (int mt = 0; mt < 2; mt++)
            xv[mt] = *(const f32x4*)&s_xT[d * XTS + we + mt * 16 + kg * 4];
        #pragma unroll
        for (int ftl = 0; ftl < 2; ftl++){
            int col = fp * 32 + ftl * 16 + r16;
            f16x8 bf[4];
            #pragma unroll
            for (int ks = 0; ks < 4; ks++){
                int j = ks * 4 + kg;
                int slot = col * 16 + (j & 8) + ((j & 7) ^ (col & 7));
                bf[ks] = s_b[cur][slot];
            }
            float b2v = b2[d * 64 + col];
            #pragma unroll
            for (int mt = 0; mt < 2; mt++){
                f32x4 acc = {b2v, b2v, b2v, b2v};
                acc = __builtin_amdgcn_mfma_f32_16x16x32_f16(ah[mt][0], bf[0], acc, 0, 0, 0);
                acc = __builtin_amdgcn_mfma_f32_16x16x32_f16(al[mt][0], bf[0], acc, 0, 0, 0);
                acc = __builtin_amdgcn_mfma_f32_16x16x32_f16(ah[mt][1], bf[1], acc, 0, 0, 0);
                acc = __builtin_amdgcn_mfma_f32_16x16x32_f16(al[mt][1], bf[1], acc, 0, 0, 0);
                acc = __builtin_amdgcn_mfma_f32_16x16x32_f16(ah[mt][2], bf[2], acc, 0, 0, 0);
                acc = __builtin_amdgcn_mfma_f32_16x16x32_f16(al[mt][2], bf[2], acc, 0, 0, 0);
                acc = __builtin_amdgcn_mfma_f32_16x16x32_f16(ah[mt][3], bf[3], acc, 0, 0, 0);
                acc = __builtin_amdgcn_mfma_f32_16x16x32_f16(al[mt][3], bf[3], acc, 0, 0, 0);
                msg[mt][ftl] = xv[mt] * acc + msg[mt][ftl];
            }
        }
        if (d < 63) STGWR(cur ^ 1);          // write late, after MFMAs
        __syncthreads();
    }
#undef STGLD
#undef STGWR

    // scatter-add: wave owns (eg edges) x (fp cols) -> each output added once
    #pragma unroll
    for (int mt = 0; mt < 2; mt++){
        #pragma unroll
        for (int r = 0; r < 4; r++){
            int el = we + mt * 16 + kg * 4 + r;
            int dt = s_dst[el];
            if (dt >= 0){
                #pragma unroll
                for (int ftl = 0; ftl < 2; ftl++)
                    atomicAdd(&m[(size_t)dt * 64 + fp * 32 + ftl * 16 + r16],
                              msg[mt][ftl][r]);
            }
        }
    }
}

// ---------------- GRU via MFMA: G = X @ W^T (3-mfma hi/lo), gate, h in-place -
// block = 32 nodes, 4 waves = (rt row-tile) x (gg: 0=gi from m, 1=gh from h).
// X converted to f16 hi/lo in-reg; W pre-converted in prep. G exchanged via
// LDS; gate fp32; m re-zeroed for next step's atomics (saves memsets).
__global__ __launch_bounds__(256) void gru_mfma_kernel(
    float* __restrict__ m, float* __restrict__ h,
    const f16* __restrict__ wf16h, const f16* __restrict__ wf16l,
    const float* __restrict__ effb, const float* __restrict__ bhh)
{
    __shared__ float s_g[2][32][194];
    const int t = threadIdx.x;
    const int base = blockIdx.x * 32;
    const int lane = t & 63;
    const int wid = t >> 6;
    const int rt = wid & 1;
    const int gg = wid >> 1;
    const int r16 = lane & 15;
    const int kg = lane >> 4;

    const float* __restrict__ X = gg ? h : m;
    int n = base + rt * 16 + r16;            // 40000 % 32 == 0 -> always valid

    f16x8 ah[2], al[2];
    #pragma unroll
    for (int ks = 0; ks < 2; ks++){
        const float* xp = X + (size_t)n * 64 + ks * 32 + kg * 8;
        f32x4 v0 = *(const f32x4*)(xp);
        f32x4 v1 = *(const f32x4*)(xp + 4);
        #pragma unroll
        for (int j = 0; j < 4; j++){
            f16 hi0 = (f16)v0[j], hi1 = (f16)v1[j];
            ah[ks][j] = hi0;     ah[ks][4 + j] = hi1;
            al[ks][j] = (f16)(v0[j] - (float)hi0);
            al[ks][4 + j] = (f16)(v1[j] - (float)hi1);
        }
    }

    const f16* __restrict__ wh = wf16h + gg * 12288;
    const f16* __restrict__ wl = wf16l + gg * 12288;
    #pragma unroll
    for (int ct = 0; ct < 12; ct++){
        int g = ct * 16 + r16;
        f16x8 bh0 = *(const f16x8*)(wh + g * 64 + kg * 8);
        f16x8 bh1 = *(const f16x8*)(wh + g * 64 + 32 + kg * 8);
        f16x8 bl0 = *(const f16x8*)(wl + g * 64 + kg * 8);
        f16x8 bl1 = *(const f16x8*)(wl + g * 64 + 32 + kg * 8);
        f32x4 acc = {0.f, 0.f, 0.f, 0.f};
        acc = __builtin_amdgcn_mfma_f32_16x16x32_f16(ah[0], bh0, acc, 0, 0, 0);
        acc = __builtin_amdgcn_mfma_f32_16x16x32_f16(ah[1], bh1, acc, 0, 0, 0);
        acc = __builtin_amdgcn_mfma_f32_16x16x32_f16(ah[0], bl0, acc, 0, 0, 0);
        acc = __builtin_amdgcn_mfma_f32_16x16x32_f16(ah[1], bl1, acc, 0, 0, 0);
        acc = __builtin_amdgcn_mfma_f32_16x16x32_f16(al[0], bh0, acc, 0, 0, 0);
        acc = __builtin_amdgcn_mfma_f32_16x16x32_f16(al[1], bh1, acc, 0, 0, 0);
        #pragma unroll
        for (int r = 0; r < 4; r++)
            s_g[gg][rt * 16 + kg * 4 + r][ct * 16 + r16] = acc[r];
    }
    __syncthreads();

    // gate: thread covers node = t>>3, f = (t&7)*8 .. +7
    int node = t >> 3;
    int f0 = (t & 7) * 8;
    int n2 = base + node;
    #pragma unroll
    for (int j = 0; j < 8; j++){
        int f = f0 + j;
        float gir = s_g[0][node][f]       + effb[f];
        float giz = s_g[0][node][64 + f]  + effb[64 + f];
        float gin = s_g[0][node][128 + f] + effb[128 + f];
        float ghr = s_g[1][node][f]       + bhh[f];
        float ghz = s_g[1][node][64 + f]  + bhh[64 + f];
        float ghn = s_g[1][node][128 + f] + bhh[128 + f];
        float r = sigmoidf_(gir + ghr);
        float z = sigmoidf_(giz + ghz);
        float nv = tanhf_(gin + r * ghn);
        size_t hb = (size_t)n2 * 64 + f;
        float hv = h[hb];
        h[hb] = (1.f - z) * nv + z * hv;
        m[hb] = 0.f;                         // re-zero for next step's atomics
    }
}

// ---------------- Set2Set + final projection: one block per graph ------------
__global__ __launch_bounds__(256) void set2set_kernel(
    const float* __restrict__ out, const int* __restrict__ offs,
    const float* __restrict__ lsT, const float* __restrict__ ls_bih,
    const float* __restrict__ ls_bhh, const float* __restrict__ lin3T,
    const float* __restrict__ lin3_b, const float* __restrict__ pred_w,
    const float* __restrict__ pred_b, float* __restrict__ e_ws,
    float* __restrict__ pred_out)
{
    int g = blockIdx.x;
    int t = threadIdx.x;
    int ln = t >> 6, d = t & 63;
    __shared__ float s_qstar[128], s_h[3][64], s_c[3][64], s_g[256];
    __shared__ float s_r[4][64], s_red[4], s_wsum[4], s_y[128];
    if (t < 128) s_qstar[t] = 0.f;
    if (t < 192){ s_h[t / 64][t % 64] = 0.f; s_c[t / 64][t % 64] = 0.f; }
    int ns = offs[g], ne = offs[g + 1];
    __syncthreads();

    for (int it = 0; it < 6; it++){
        for (int l = 0; l < 3; l++){
            const float* xv = (l == 0) ? s_qstar : s_h[l - 1];
            int xdim = (l == 0) ? 128 : 64;
            const float* wxT = lsT + ((l == 0) ? 0 : (32768 + (l - 1) * 16384));
            const float* whT = lsT + 65536 + l * 16384;
            float acc = ls_bih[l * 256 + t] + ls_bhh[l * 256 + t];
            for (int j = 0; j < xdim; j++) acc = fmaf(xv[j], wxT[j * 256 + t], acc);
            #pragma unroll 4
            for (int j = 0; j < 64; j++) acc = fmaf(s_h[l][j], whT[j * 256 + t], acc);
            __syncthreads();
            s_g[t] = acc;
            __syncthreads();
            if (t < 64){
                float iv = s_g[t], fv = s_g[64 + t], gv = s_g[128 + t], ov = s_g[192 + t];
                float c2 = sigmoidf_(fv) * s_c[l][t] + sigmoidf_(iv) * tanhf_(gv);
                float h2 = sigmoidf_(ov) * tanhf_(c2);
                s_c[l][t] = c2; s_h[l][t] = h2;
            }
            __syncthreads();
        }
        float wmax = -3.4e38f;
        for (int n = ns + ln; n < ne; n += 4){
            float p = out[(size_t)n * 64 + d] * s_h[2][d];
            #pragma unroll
            for (int o = 1; o < 64; o <<= 1) p += __shfl_xor(p, o);
            if (d == 0) e_ws[n] = p;
            wmax = fmaxf(wmax, p);
        }
        if (d == 0) s_red[ln] = wmax;
        __syncthreads();
        float gmax = fmaxf(fmaxf(s_red[0], s_red[1]), fmaxf(s_red[2], s_red[3]));
        float wsum = 0.f, racc = 0.f;
        for (int n = ns + ln; n < ne; n += 4){
            float w = __expf(e_ws[n] - gmax);
            wsum += w;
            racc = fmaf(w, out[(size_t)n * 64 + d], racc);
        }
        s_r[ln][d] = racc;
        if (d == 0) s_wsum[ln] = wsum;
        __syncthreads();
        if (t < 64){
            float gsum = s_wsum[0] + s_wsum[1] + s_wsum[2] + s_wsum[3];
            float ro = s_r[0][t] + s_r[1][t] + s_r[2][t] + s_r[3][t];
            ro = (gsum > 0.f) ? ro / gsum : 0.f;
            s_qstar[t] = s_h[2][t];
            s_qstar[64 + t] = ro;
        }
        __syncthreads();
    }
    if (t < 128){
        float acc = lin3_b[t];
        #pragma unroll 4
        for (int i = 0; i < 128; i++) acc = fmaf(s_qstar[i], lin3T[i * 128 + t], acc);
        s_y[t] = fmaxf(acc, 0.f);
    }
    __syncthreads();
    if (t < 64){
        float p = s_y[t] * pred_w[t] + s_y[64 + t] * pred_w[64 + t];
        #pragma unroll
        for (int o = 1; o < 64; o <<= 1) p += __shfl_xor(p, o);
        if (t == 0) pred_out[g] = p + pred_b[0];
    }
}

extern "C" void kernel_launch(void* const* d_in, const int* in_sizes, int n_in,
                              void* d_out, int out_size, void* d_ws, size_t ws_size,
                              hipStream_t stream)
{
    (void)in_sizes; (void)n_in; (void)out_size; (void)ws_size;
    const float* n_feat  = (const float*)d_in[0];
    const float* e_feat  = (const float*)d_in[1];
    const int*   src     = (const int*)d_in[2];
    const int*   dst     = (const int*)d_in[3];
    const int*   node_graph = (const int*)d_in[4];
    const float* lin0_w  = (const float*)d_in[6];
    const float* lin0_b  = (const float*)d_in[7];
    const float* en_w1   = (const float*)d_in[8];
    const float* en_b1   = (const float*)d_in[9];
    const float* en_w2   = (const float*)d_in[10];
    const float* en_b2   = (const float*)d_in[11];
    const float* conv_b  = (const float*)d_in[12];
    const float* gru_wih = (const float*)d_in[13];
    const float* gru_whh = (const float*)d_in[14];
    const float* gru_bih = (const float*)d_in[15];
    const float* gru_bhh = (const float*)d_in[16];
    const float* ls_wih0 = (const float*)d_in[17];
    const float* ls_wih12= (const float*)d_in[18];
    const float* ls_whh  = (const float*)d_in[19];
    const float* ls_bih  = (const float*)d_in[20];
    const float* ls_bhh  = (const float*)d_in[21];
    const float* lin3_w  = (const float*)d_in[22];
    const float* lin3_b  = (const float*)d_in[23];
    const float* pred_w  = (const float*)d_in[24];
    const float* pred_b  = (const float*)d_in[25];

    float* h = (float*)d_out;                       // N x 64 (also "out")
    float* pred_out = (float*)d_out + (size_t)NN * 64;

    char* ws = (char*)d_ws;
    f16*   hidh  = (f16*)(ws + 0);                  // 25,600,000
    f16*   hidl  = (f16*)(ws + 25600000);           // 25,600,000
    float* m     = (float*)(ws + 51200000);         // 10,240,000
    f16*   w2h   = (f16*)(ws + 61440000);           //  1,048,576
    f16*   wf16h = (f16*)(ws + 62488576);           //     49,152
    f16*   wf16l = (f16*)(ws + 62537728);           //     49,152
    float* lsT   = (float*)(ws + 62586880);         //    458,752
    float* lin3T = (float*)(ws + 63045632);         //     65,536
    float* effb  = (float*)(ws + 63111168);         //        768
    float* e_ws  = (float*)(ws + 63111936);         //    160,000
    int*   offs  = (int*)(ws + 63271936);           //      1,028

    prep_kernel<<<2754, 256, 0, stream>>>(en_w2, w2h, gru_wih, gru_whh,
                                          wf16h, wf16l,
                                          ls_wih0, ls_wih12, ls_whh, lsT,
                                          lin3_w, lin3T, gru_bih, conv_b, effb,
                                          node_graph, offs);
    lin0_kernel<<<(NN * 64) / 256, 256, 0, stream>>>(n_feat, lin0_w, lin0_b, h);
    edge_hidden_kernel<<<(EE * 128) / 256, 256, 0, stream>>>(e_feat, en_w1, en_b1, hidh, hidl);
    hipMemsetAsync(m, 0, (size_t)NN * 64 * sizeof(float), stream);

    for (int step = 0; step < 6; step++){
        msg_fused_kernel<<<(EE + EPB - 1) / EPB, 256, 0, stream>>>(h, hidh, hidl, w2h,
                                                                   en_b2, src, dst, m);
        gru_mfma_kernel<<<NN / 32, 256, 0, stream>>>(m, h, wf16h, wf16l, effb, gru_bhh);
    }

    set2set_kernel<<<BB, 256, 0, stream>>>(h, offs, lsT, ls_bih, ls_bhh,
                                           lin3T, lin3_b, pred_w, pred_b,
                                           e_ws, pred_out);
}

// Round 14
// 1717.554 us; speedup vs baseline: 1.6335x; 1.0496x over previous
//
#include <hip/hip_runtime.h>

typedef unsigned short u16;
typedef unsigned int u32;
typedef _Float16 f16;
typedef __attribute__((ext_vector_type(8))) _Float16 f16x8;
typedef __attribute__((ext_vector_type(4))) float f32x4;

#define NN 40000
#define EE 100000
#define DD 64
#define BB 256
#define XTS 68   // s_xT stride (f32): 16B-aligned rows
#define EPB 64   // edges per block; 4 waves = 2 edge-groups x 2 col-pairs

__device__ inline float sigmoidf_(float x){
    return 1.f / (1.f + __expf(-x));
}
__device__ inline float tanhf_(float x){
    x = fmaxf(fminf(x, 15.f), -15.f);
    float e = __expf(2.f * x);
    return (e - 1.f) / (e + 1.f);
}

typedef __attribute__((address_space(3))) unsigned int lds_u32;
typedef __attribute__((address_space(1))) const unsigned int g_u32;
__device__ inline void gload_lds16(const void* g, void* l){
    __builtin_amdgcn_global_load_lds((g_u32*)g, (lds_u32*)l, 16, 0, 0);
}

// ---------------- prep: converts, transposes, eff bias, offsets --------------
__global__ __launch_bounds__(256) void prep_kernel(
    const float* __restrict__ en_w2, f16* __restrict__ w2h,
    const float* __restrict__ gru_wih, const float* __restrict__ gru_whh,
    f16* __restrict__ wf16h, f16* __restrict__ wf16l,
    const float* __restrict__ ls_wih0, const float* __restrict__ ls_wih12,
    const float* __restrict__ ls_whh, float* __restrict__ lsT,
    const float* __restrict__ lin3_w, float* __restrict__ lin3T,
    const float* __restrict__ gru_bih, const float* __restrict__ conv_b,
    float* __restrict__ effb,
    const int* __restrict__ node_graph, int* __restrict__ offs)
{
    int i = blockIdx.x * 256 + threadIdx.x;
    if (i < 524288){
        w2h[i] = (f16)en_w2[i];
        return;
    }
    i -= 524288;
    if (i < 49152){                       // GRU weights -> f16 hi/lo, [gg][g][d]
        int sel = i / 12288;              // 0:ih-hi 1:ih-lo 2:hh-hi 3:hh-lo
        int r = i % 12288;
        int gg = sel >> 1, islo = sel & 1;
        float v = (gg ? gru_whh : gru_wih)[r];
        f16 hi = (f16)v;
        if (islo) wf16l[gg * 12288 + r] = (f16)(v - (float)hi);
        else      wf16h[gg * 12288 + r] = hi;
        return;
    }
    i -= 49152;
    if (i < 114688){
        float v;
        if (i < 32768){
            int d = i >> 8, g = i & 255;
            v = ls_wih0[g * 128 + d];
        } else if (i < 65536){
            int j = i - 32768;
            int l = j >> 14, r = j & 16383;
            int d = r >> 8, g = r & 255;
            v = ls_wih12[l * 16384 + g * 64 + d];
        } else {
            int j = i - 65536;
            int l = j >> 14, r = j & 16383;
            int d = r >> 8, g = r & 255;
            v = ls_whh[l * 16384 + g * 64 + d];
        }
        lsT[i] = v;
        return;
    }
    i -= 114688;
    if (i < 16384){
        int ii = i >> 7, jj = i & 127;
        lin3T[i] = lin3_w[jj * 128 + ii];
        return;
    }
    i -= 16384;
    if (i < 192){
        float b = gru_bih[i];
        #pragma unroll
        for (int d = 0; d < 64; d++) b += gru_wih[i * 64 + d] * conv_b[d];
        effb[i] = b;
        return;
    }
    i -= 192;
    if (i <= 256){
        int lo = 0, hi = NN;
        while (lo < hi){
            int mid = (lo + hi) >> 1;
            if (node_graph[mid] < i) lo = mid + 1; else hi = mid;
        }
        offs[i] = lo;
        return;
    }
}

// ---------------- lin0: out = n_feat @ lin0_w^T + b  (writes h in d_out) -----
__global__ __launch_bounds__(256) void lin0_kernel(
    const float* __restrict__ nf, const float* __restrict__ w,
    const float* __restrict__ b, float* __restrict__ out)
{
    int tid = blockIdx.x * 256 + threadIdx.x;
    int n = tid >> 6, d = tid & 63;
    if (n >= NN) return;
    float acc = b[d];
    const float* nr = nf + (size_t)n * 23;
    const float* wr = w + d * 23;
    #pragma unroll
    for (int j = 0; j < 23; j++) acc = fmaf(nr[j], wr[j], acc);
    out[(size_t)n * 64 + d] = acc;
}

// ---------------- edge hidden: relu(e_feat @ w1^T + b1) -> f16 hi/lo ---------
__global__ __launch_bounds__(256) void edge_hidden_kernel(
    const float* __restrict__ ef, const float* __restrict__ w1,
    const float* __restrict__ b1, f16* __restrict__ hidh, f16* __restrict__ hidl)
{
    int tid = blockIdx.x * 256 + threadIdx.x;
    int e = tid >> 7, k = tid & 127;
    if (e >= EE) return;
    float acc = b1[k];
    const float* er = ef + (size_t)e * 19;
    const float* wr = w1 + k * 19;
    #pragma unroll
    for (int j = 0; j < 19; j++) acc = fmaf(er[j], wr[j], acc);
    acc = fmaxf(acc, 0.f);
    f16 hi = (f16)acc;
    f16 lo = (f16)(acc - (float)hi);
    hidh[(size_t)e * 128 + k] = hi;
    hidl[(size_t)e * 128 + k] = lo;
}

// ---------------- fused msg: async-DMA B staging, R12 conflict-free layout ---
// msg[e,f] = sum_d x[e,d] * ( sum_k u[e,k]*W2[d*64+f,k] + b2[d*64+f] )
// block = 64 edges; wave (eg, fp) owns edges [eg*32,+32) x cols [fp*32,+32),
// full K in regs (A hi/lo 64 VGPR), one barrier per d.
// B layout: slot = kh*512 + col*8 + (piece ^ (col&7)) -- byte-identical to
// R12's measured ~0-B-read-conflict layout. Staged via global_load_lds
// width=16 (m97): linear LDS dest (wave base + lane*16) + pre-swizzled
// global source (rule #21); no stage regs, no ds_write, DMA completes at
// the existing barrier's vmcnt drain.
__global__ __launch_bounds__(256) void msg_fused_kernel(
    const float* __restrict__ h, const f16* __restrict__ hidh,
    const f16* __restrict__ hidl, const f16* __restrict__ w2h,
    const float* __restrict__ b2, const int* __restrict__ src,
    const int* __restrict__ dst, float* __restrict__ m)
{
    __shared__ float s_xT[64 * XTS];         // [d][el] transposed x
    __shared__ int s_dst[EPB];
    __shared__ f16x8 s_bb[2][1024];          // 2 x 16 KB B tiles (2 half-K subtiles)

    const int t = threadIdx.x;
    const int base = blockIdx.x * EPB;
    const int lane = t & 63;
    const int wid = t >> 6;

    // per-lane pre-swizzled global source offsets (d-invariant, f16 elems):
    // slot s = wid*256 + cc*64 + lane; kh=s>>9, col=(s&511)>>3, p=s&7,
    // jj = p ^ (col&7); off = col*128 + kh*64 + jj*8
    int goff[4];
    #pragma unroll
    for (int cc = 0; cc < 4; cc++){
        int s = wid * 256 + cc * 64 + lane;
        int kh = s >> 9;
        int c2 = s & 511;
        int col = c2 >> 3;
        int jj = (c2 & 7) ^ (col & 7);
        goff[cc] = col * 128 + kh * 64 + jj * 8;
    }

#define STG_ISSUE(DN, BUF)                                                   \
    {                                                                        \
        const f16* gsrc = w2h + (size_t)(DN) * 8192;                         \
        _Pragma("unroll")                                                    \
        for (int cc = 0; cc < 4; cc++)                                       \
            gload_lds16(gsrc + goff[cc], &s_bb[BUF][wid * 256 + cc * 64]);   \
    }

    STG_ISSUE(0, 0);                         // DMA tile 0 while we stage x

    for (int i = t; i < EPB * 64; i += 256){
        int el = i >> 6, f = i & 63;
        int e = base + el;
        float v = 0.f;
        if (e < EE) v = h[(size_t)src[e] * 64 + f];
        s_xT[f * XTS + el] = v;
    }
    if (t < EPB){
        int e = base + t;
        s_dst[t] = (e < EE) ? dst[e] : -1;
    }

    const int eg = wid >> 1;                 // edge group: 32 edges
    const int fp = wid & 1;                  // col pair: cols fp*32..fp*32+31
    const int r16 = lane & 15;
    const int kg = lane >> 4;
    const int we = eg * 32;
    const int sw = r16 & 7;

    // A fragments (hi and lo), full K: 16 frags = 64 VGPR
    f16x8 ah[2][4], al[2][4];
    #pragma unroll
    for (int mt = 0; mt < 2; mt++){
        int e = base + we + mt * 16 + r16;
        #pragma unroll
        for (int ks = 0; ks < 4; ks++){
            if (e < EE){
                ah[mt][ks] = *(const f16x8*)(hidh + (size_t)e * 128 + ks * 32 + kg * 8);
                al[mt][ks] = *(const f16x8*)(hidl + (size_t)e * 128 + ks * 32 + kg * 8);
            } else {
                f16x8 z = {0,0,0,0,0,0,0,0};
                ah[mt][ks] = z; al[mt][ks] = z;
            }
        }
    }

    f32x4 msg[2][2];                         // [mt][ftl]: 16 VGPR
    #pragma unroll
    for (int a = 0; a < 2; a++)
        #pragma unroll
        for (int b = 0; b < 2; b++){
            f32x4 z = {0.f, 0.f, 0.f, 0.f};
            msg[a][b] = z;
        }

    // d-invariant B-read slots: for ftl, ks: kh=ks>>1, j2=(ks&1)*4+kg,
    // slot = kh*512 + col*8 + (j2 ^ sw)
    int rslot[2][4];
    #pragma unroll
    for (int ftl = 0; ftl < 2; ftl++){
        int col = fp * 32 + ftl * 16 + r16;
        #pragma unroll
        for (int ks = 0; ks < 4; ks++){
            int j2 = (ks & 1) * 4 + kg;
            rslot[ftl][ks] = (ks >> 1) * 512 + col * 8 + (j2 ^ sw);
        }
    }

    __syncthreads();                         // tile 0 DMA + s_xT/s_dst complete

    for (int d = 0; d < 64; d++){
        int cur = d & 1;
        if (d < 63) STG_ISSUE(d + 1, cur ^ 1);   // async DMA next tile
        f32x4 xv[2];
        #pragma unroll
        for (int mt = 0; mt < 2; mt++)
            xv[mt] = *(const f32x4*)&s_xT[d * XTS + we + mt * 16 + kg * 4];
        #pragma unroll
        for (int ftl = 0; ftl < 2; ftl++){
            f16x8 bf0 = s_bb[cur][rslot[ftl][0]];
            f16x8 bf1 = s_bb[cur][rslot[ftl][1]];
            f16x8 bf2 = s_bb[cur][rslot[ftl][2]];
            f16x8 bf3 = s_bb[cur][rslot[ftl][3]];
            float b2v = b2[d * 64 + fp * 32 + ftl * 16 + r16];
            #pragma unroll
            for (int mt = 0; mt < 2; mt++){
                f32x4 acc = {b2v, b2v, b2v, b2v};
                acc = __builtin_amdgcn_mfma_f32_16x16x32_f16(ah[mt][0], bf0, acc, 0, 0, 0);
                acc = __builtin_amdgcn_mfma_f32_16x16x32_f16(al[mt][0], bf0, acc, 0, 0, 0);
                acc = __builtin_amdgcn_mfma_f32_16x16x32_f16(ah[mt][1], bf1, acc, 0, 0, 0);
                acc = __builtin_amdgcn_mfma_f32_16x16x32_f16(al[mt][1], bf1, acc, 0, 0, 0);
                acc = __builtin_amdgcn_mfma_f32_16x16x32_f16(ah[mt][2], bf2, acc, 0, 0, 0);
                acc = __builtin_amdgcn_mfma_f32_16x16x32_f16(al[mt][2], bf2, acc, 0, 0, 0);
                acc = __builtin_amdgcn_mfma_f32_16x16x32_f16(ah[mt][3], bf3, acc, 0, 0, 0);
                acc = __builtin_amdgcn_mfma_f32_16x16x32_f16(al[mt][3], bf3, acc, 0, 0, 0);
                msg[mt][ftl] = xv[mt] * acc + msg[mt][ftl];
            }
        }
        __syncthreads();                     // vmcnt drain -> next tile ready
    }
#undef STG_ISSUE

    // scatter-add: wave owns (eg edges) x (fp cols) -> each output added once
    #pragma unroll
    for (int mt = 0; mt < 2; mt++){
        #pragma unroll
        for (int r = 0; r < 4; r++){
            int el = we + mt * 16 + kg * 4 + r;
            int dt = s_dst[el];
            if (dt >= 0){
                #pragma unroll
                for (int ftl = 0; ftl < 2; ftl++)
                    atomicAdd(&m[(size_t)dt * 64 + fp * 32 + ftl * 16 + r16],
                              msg[mt][ftl][r]);
            }
        }
    }
}

// ---------------- GRU via MFMA: G = X @ W^T (3-mfma hi/lo), gate, h in-place -
__global__ __launch_bounds__(256) void gru_mfma_kernel(
    float* __restrict__ m, float* __restrict__ h,
    const f16* __restrict__ wf16h, const f16* __restrict__ wf16l,
    const float* __restrict__ effb, const float* __restrict__ bhh)
{
    __shared__ float s_g[2][32][194];
    const int t = threadIdx.x;
    const int base = blockIdx.x * 32;
    const int lane = t & 63;
    const int wid = t >> 6;
    const int rt = wid & 1;
    const int gg = wid >> 1;
    const int r16 = lane & 15;
    const int kg = lane >> 4;

    const float* __restrict__ X = gg ? h : m;
    int n = base + rt * 16 + r16;            // 40000 % 32 == 0 -> always valid

    f16x8 ah[2], al[2];
    #pragma unroll
    for (int ks = 0; ks < 2; ks++){
        const float* xp = X + (size_t)n * 64 + ks * 32 + kg * 8;
        f32x4 v0 = *(const f32x4*)(xp);
        f32x4 v1 = *(const f32x4*)(xp + 4);
        #pragma unroll
        for (int j = 0; j < 4; j++){
            f16 hi0 = (f16)v0[j], hi1 = (f16)v1[j];
            ah[ks][j] = hi0;     ah[ks][4 + j] = hi1;
            al[ks][j] = (f16)(v0[j] - (float)hi0);
            al[ks][4 + j] = (f16)(v1[j] - (float)hi1);
        }
    }

    const f16* __restrict__ wh = wf16h + gg * 12288;
    const f16* __restrict__ wl = wf16l + gg * 12288;
    #pragma unroll
    for (int ct = 0; ct < 12; ct++){
        int g = ct * 16 + r16;
        f16x8 bh0 = *(const f16x8*)(wh + g * 64 + kg * 8);
        f16x8 bh1 = *(const f16x8*)(wh + g * 64 + 32 + kg * 8);
        f16x8 bl0 = *(const f16x8*)(wl + g * 64 + kg * 8);
        f16x8 bl1 = *(const f16x8*)(wl + g * 64 + 32 + kg * 8);
        f32x4 acc = {0.f, 0.f, 0.f, 0.f};
        acc = __builtin_amdgcn_mfma_f32_16x16x32_f16(ah[0], bh0, acc, 0, 0, 0);
        acc = __builtin_amdgcn_mfma_f32_16x16x32_f16(ah[1], bh1, acc, 0, 0, 0);
        acc = __builtin_amdgcn_mfma_f32_16x16x32_f16(ah[0], bl0, acc, 0, 0, 0);
        acc = __builtin_amdgcn_mfma_f32_16x16x32_f16(ah[1], bl1, acc, 0, 0, 0);
        acc = __builtin_amdgcn_mfma_f32_16x16x32_f16(al[0], bh0, acc, 0, 0, 0);
        acc = __builtin_amdgcn_mfma_f32_16x16x32_f16(al[1], bh1, acc, 0, 0, 0);
        #pragma unroll
        for (int r = 0; r < 4; r++)
            s_g[gg][rt * 16 + kg * 4 + r][ct * 16 + r16] = acc[r];
    }
    __syncthreads();

    int node = t >> 3;
    int f0 = (t & 7) * 8;
    int n2 = base + node;
    #pragma unroll
    for (int j = 0; j < 8; j++){
        int f = f0 + j;
        float gir = s_g[0][node][f]       + effb[f];
        float giz = s_g[0][node][64 + f]  + effb[64 + f];
        float gin = s_g[0][node][128 + f] + effb[128 + f];
        float ghr = s_g[1][node][f]       + bhh[f];
        float ghz = s_g[1][node][64 + f]  + bhh[64 + f];
        float ghn = s_g[1][node][128 + f] + bhh[128 + f];
        float r = sigmoidf_(gir + ghr);
        float z = sigmoidf_(giz + ghz);
        float nv = tanhf_(gin + r * ghn);
        size_t hb = (size_t)n2 * 64 + f;
        float hv = h[hb];
        h[hb] = (1.f - z) * nv + z * hv;
        m[hb] = 0.f;                         // re-zero for next step's atomics
    }
}

// ---------------- Set2Set + final projection: one block per graph ------------
__global__ __launch_bounds__(256) void set2set_kernel(
    const float* __restrict__ out, const int* __restrict__ offs,
    const float* __restrict__ lsT, const float* __restrict__ ls_bih,
    const float* __restrict__ ls_bhh, const float* __restrict__ lin3T,
    const float* __restrict__ lin3_b, const float* __restrict__ pred_w,
    const float* __restrict__ pred_b, float* __restrict__ e_ws,
    float* __restrict__ pred_out)
{
    int g = blockIdx.x;
    int t = threadIdx.x;
    int ln = t >> 6, d = t & 63;
    __shared__ float s_qstar[128], s_h[3][64], s_c[3][64], s_g[256];
    __shared__ float s_r[4][64], s_red[4], s_wsum[4], s_y[128];
    if (t < 128) s_qstar[t] = 0.f;
    if (t < 192){ s_h[t / 64][t % 64] = 0.f; s_c[t / 64][t % 64] = 0.f; }
    int ns = offs[g], ne = offs[g + 1];
    __syncthreads();

    for (int it = 0; it < 6; it++){
        for (int l = 0; l < 3; l++){
            const float* xv = (l == 0) ? s_qstar : s_h[l - 1];
            int xdim = (l == 0) ? 128 : 64;
            const float* wxT = lsT + ((l == 0) ? 0 : (32768 + (l - 1) * 16384));
            const float* whT = lsT + 65536 + l * 16384;
            float acc = ls_bih[l * 256 + t] + ls_bhh[l * 256 + t];
            for (int j = 0; j < xdim; j++) acc = fmaf(xv[j], wxT[j * 256 + t], acc);
            #pragma unroll 4
            for (int j = 0; j < 64; j++) acc = fmaf(s_h[l][j], whT[j * 256 + t], acc);
            __syncthreads();
            s_g[t] = acc;
            __syncthreads();
            if (t < 64){
                float iv = s_g[t], fv = s_g[64 + t], gv = s_g[128 + t], ov = s_g[192 + t];
                float c2 = sigmoidf_(fv) * s_c[l][t] + sigmoidf_(iv) * tanhf_(gv);
                float h2 = sigmoidf_(ov) * tanhf_(c2);
                s_c[l][t] = c2; s_h[l][t] = h2;
            }
            __syncthreads();
        }
        float wmax = -3.4e38f;
        for (int n = ns + ln; n < ne; n += 4){
            float p = out[(size_t)n * 64 + d] * s_h[2][d];
            #pragma unroll
            for (int o = 1; o < 64; o <<= 1) p += __shfl_xor(p, o);
            if (d == 0) e_ws[n] = p;
            wmax = fmaxf(wmax, p);
        }
        if (d == 0) s_red[ln] = wmax;
        __syncthreads();
        float gmax = fmaxf(fmaxf(s_red[0], s_red[1]), fmaxf(s_red[2], s_red[3]));
        float wsum = 0.f, racc = 0.f;
        for (int n = ns + ln; n < ne; n += 4){
            float w = __expf(e_ws[n] - gmax);
            wsum += w;
            racc = fmaf(w, out[(size_t)n * 64 + d], racc);
        }
        s_r[ln][d] = racc;
        if (d == 0) s_wsum[ln] = wsum;
        __syncthreads();
        if (t < 64){
            float gsum = s_wsum[0] + s_wsum[1] + s_wsum[2] + s_wsum[3];
            float ro = s_r[0][t] + s_r[1][t] + s_r[2][t] + s_r[3][t];
            ro = (gsum > 0.f) ? ro / gsum : 0.f;
            s_qstar[t] = s_h[2][t];
            s_qstar[64 + t] = ro;
        }
        __syncthreads();
    }
    if (t < 128){
        float acc = lin3_b[t];
        #pragma unroll 4
        for (int i = 0; i < 128; i++) acc = fmaf(s_qstar[i], lin3T[i * 128 + t], acc);
        s_y[t] = fmaxf(acc, 0.f);
    }
    __syncthreads();
    if (t < 64){
        float p = s_y[t] * pred_w[t] + s_y[64 + t] * pred_w[64 + t];
        #pragma unroll
        for (int o = 1; o < 64; o <<= 1) p += __shfl_xor(p, o);
        if (t == 0) pred_out[g] = p + pred_b[0];
    }
}

extern "C" void kernel_launch(void* const* d_in, const int* in_sizes, int n_in,
                              void* d_out, int out_size, void* d_ws, size_t ws_size,
                              hipStream_t stream)
{
    (void)in_sizes; (void)n_in; (void)out_size; (void)ws_size;
    const float* n_feat  = (const float*)d_in[0];
    const float* e_feat  = (const float*)d_in[1];
    const int*   src     = (const int*)d_in[2];
    const int*   dst     = (const int*)d_in[3];
    const int*   node_graph = (const int*)d_in[4];
    const float* lin0_w  = (const float*)d_in[6];
    const float* lin0_b  = (const float*)d_in[7];
    const float* en_w1   = (const float*)d_in[8];
    const float* en_b1   = (const float*)d_in[9];
    const float* en_w2   = (const float*)d_in[10];
    const float* en_b2   = (const float*)d_in[11];
    const float* conv_b  = (const float*)d_in[12];
    const float* gru_wih = (const float*)d_in[13];
    const float* gru_whh = (const float*)d_in[14];
    const float* gru_bih = (const float*)d_in[15];
    const float* gru_bhh = (const float*)d_in[16];
    const float* ls_wih0 = (const float*)d_in[17];
    const float* ls_wih12= (const float*)d_in[18];
    const float* ls_whh  = (const float*)d_in[19];
    const float* ls_bih  = (const float*)d_in[20];
    const float* ls_bhh  = (const float*)d_in[21];
    const float* lin3_w  = (const float*)d_in[22];
    const float* lin3_b  = (const float*)d_in[23];
    const float* pred_w  = (const float*)d_in[24];
    const float* pred_b  = (const float*)d_in[25];

    float* h = (float*)d_out;                       // N x 64 (also "out")
    float* pred_out = (float*)d_out + (size_t)NN * 64;

    char* ws = (char*)d_ws;
    f16*   hidh  = (f16*)(ws + 0);                  // 25,600,000
    f16*   hidl  = (f16*)(ws + 25600000);           // 25,600,000
    float* m     = (float*)(ws + 51200000);         // 10,240,000
    f16*   w2h   = (f16*)(ws + 61440000);           //  1,048,576
    f16*   wf16h = (f16*)(ws + 62488576);           //     49,152
    f16*   wf16l = (f16*)(ws + 62537728);           //     49,152
    float* lsT   = (float*)(ws + 62586880);         //    458,752
    float* lin3T = (float*)(ws + 63045632);         //     65,536
    float* effb  = (float*)(ws + 63111168);         //        768
    float* e_ws  = (float*)(ws + 63111936);         //    160,000
    int*   offs  = (int*)(ws + 63271936);           //      1,028

    prep_kernel<<<2754, 256, 0, stream>>>(en_w2, w2h, gru_wih, gru_whh,
                                          wf16h, wf16l,
                                          ls_wih0, ls_wih12, ls_whh, lsT,
                                          lin3_w, lin3T, gru_bih, conv_b, effb,
                                          node_graph, offs);
    lin0_kernel<<<(NN * 64) / 256, 256, 0, stream>>>(n_feat, lin0_w, lin0_b, h);
    edge_hidden_kernel<<<(EE * 128) / 256, 256, 0, stream>>>(e_feat, en_w1, en_b1, hidh, hidl);
    hipMemsetAsync(m, 0, (size_t)NN * 64 * sizeof(float), stream);

    for (int step = 0; step < 6; step++){
        msg_fused_kernel<<<(EE + EPB - 1) / EPB, 256, 0, stream>>>(h, hidh, hidl, w2h,
                                                                   en_b2, src, dst, m);
        gru_mfma_kernel<<<NN / 32, 256, 0, stream>>>(m, h, wf16h, wf16l, effb, gru_bhh);
    }

    set2set_kernel<<<BB, 256, 0, stream>>>(h, offs, lsT, ls_bih, ls_bhh,
                                           lin3T, lin3_b, pred_w, pred_b,
                                           e_ws, pred_out);
}